// Round 1
// 349.054 us; speedup vs baseline: 1.2585x; 1.2585x over previous
//
#include <hip/hip_runtime.h>
#include <math.h>

#define NN 512
#define NC 3

// Radial cutoff envelope e[i][j] = (r<4.5)/r, r=sqrt((i+1)^2+(j+1)^2), i,j in 0..3
__device__ __constant__ float d_env[16] = {
    0.70710678f, 0.44721360f, 0.31622777f, 0.24253563f,
    0.44721360f, 0.35355339f, 0.27735010f, 0.22360680f,
    0.31622777f, 0.27735010f, 0.23570226f, 0.00000000f,
    0.24253563f, 0.22360680f, 0.00000000f, 0.00000000f
};

// p-major sine table only: ws[p*4 + j] = sin(pi * p * (j+1) / 511), p in 0..511.
// One float4 load at ws + 4*p yields all 4 harmonics for coordinate p.
__global__ __launch_bounds__(256) void sine_table_kernel(float* __restrict__ ws) {
    const int t = blockIdx.x * 256 + threadIdx.x;   // 2048 threads
    const int j = t & 3;
    const int p = t >> 2;
    ws[t] = sinf((float)M_PI * (float)p * (1.0f / 511.0f) * (float)(j + 1));
}

// One block = one (b, y) row. 256 threads, each thread owns pixels x=tid and
// x=tid+256  ->  adjacent lanes touch adjacent pixels, so every gather
// instruction spans ~4-5 cache lines instead of 16 (the old 4-px-per-thread
// mapping strided lanes by 16 B).
__global__ __launch_bounds__(256) void diffeo_kernel(
    const float* __restrict__ xin,
    const float* __restrict__ Fx,
    const float* __restrict__ Fy,
    float* __restrict__ out,
    const float* __restrict__ ws,
    float scale)
{
    const int tid = threadIdx.x;
    const int bid = blockIdx.x;
    // XCD-contiguous row assignment: 32768 blocks, 8 XCDs, bijective since
    // 32768 % 8 == 0. XCD k gets rows [k*4096, (k+1)*4096) -> vertically
    // overlapping gather bands stay in one XCD's L2.
    const int row = ((bid & 7) << 12) | (bid >> 3);
    const int b = row >> 9;                  // wave-uniform
    const int y = row & (NN - 1);

    // per-row sine vector sy[j] (one float4 load)
    const float4 sy = *(const float4*)(ws + y * 4);
    const float syv[4] = { sy.x, sy.y, sy.z, sy.w };

    // fold F*e*sy over j, scale included: cu[i] = scale * sum_j F[b,i,j]*e[i,j]*sy[j]
    const float* fx = Fx + b * 16;
    const float* fy = Fy + b * 16;
    float cu[4], cv[4];
#pragma unroll
    for (int i = 0; i < 4; ++i) {
        float su = 0.0f, sv = 0.0f;
#pragma unroll
        for (int j = 0; j < 4; ++j) {
            const float w = d_env[i * 4 + j] * syv[j];
            su += fx[i * 4 + j] * w;
            sv += fy[i * 4 + j] * w;
        }
        cu[i] = scale * su;
        cv[i] = scale * sv;
    }

    const float* __restrict__ base  = xin + (size_t)b * NC * NN * NN;
    float* __restrict__       obase = out + (size_t)b * NC * NN * NN + (size_t)y * NN;
    const float yr = (float)y;

#pragma unroll
    for (int p = 0; p < 2; ++p) {
        const int xx = tid + (p << 8);

        // sx[i] for this pixel: one float4 load from the p-major table
        const float4 sx = *(const float4*)(ws + xx * 4);
        const float du = sx.x * cu[0] + sx.y * cu[1] + sx.z * cu[2] + sx.w * cu[3];
        const float dv = sx.x * cv[0] + sx.y * cv[1] + sx.z * cv[2] + sx.w * cv[3];

        const float xn = fminf(fmaxf((float)xx - du, 0.0f), 511.0f);
        const float yn = fminf(fmaxf(yr - dv, 0.0f), 511.0f);
        const float xff = floorf(xn), yff = floorf(yn);
        const int xf = (int)xff, yf = (int)yff;
        const int xc = min(xf + 1, NN - 1);   // == ceil for non-integer xn; weight 0 otherwise
        const int yc = min(yf + 1, NN - 1);
        const float xv = xn - xff, yv = yn - yff;

        const int o00 = yf * NN + xf;
        const int o01 = yf * NN + xc;
        const int o10 = yc * NN + xf;
        const int o11 = yc * NN + xc;

#pragma unroll
        for (int c = 0; c < NC; ++c) {
            const float* img = base + c * NN * NN;
            const float v00 = img[o00];
            const float v01 = img[o01];
            const float v10 = img[o10];
            const float v11 = img[o11];
            const float top = v00 + xv * (v01 - v00);
            const float bot = v10 + xv * (v11 - v10);
            obase[c * NN * NN + xx] = top + yv * (bot - top);   // coalesced scalar store
        }
    }
}

extern "C" void kernel_launch(void* const* d_in, const int* in_sizes, int n_in,
                              void* d_out, int out_size, void* d_ws, size_t ws_size,
                              hipStream_t stream) {
    const float* x  = (const float*)d_in[0];
    const float* Fx = (const float*)d_in[1];
    const float* Fy = (const float*)d_in[2];
    float* out = (float*)d_out;
    float* ws  = (float*)d_ws;   // 8 KB sine table (re-built every call; ws re-poisoned)

    // typ = n * sqrt(pi*log(cut)) / 2 ; scale = sqrt(T/typ^2) * n
    const double typ = 512.0 * sqrt(M_PI * log(4.0)) / 2.0;
    const float scale = (float)(sqrt(0.01 / (typ * typ)) * 512.0);

    sine_table_kernel<<<8, 256, 0, stream>>>(ws);
    diffeo_kernel<<<64 * 512, 256, 0, stream>>>(x, Fx, Fy, out, ws, scale);
}